// Round 7
// baseline (321.092 us; speedup 1.0000x reference)
//
#include <hip/hip_runtime.h>

// LSTM(units=64) over T=5, D_IN=1, then Dense(1, relu).
// R20 = deconfounded occupancy test: persistent 2-chunk blocks.
// R19 post-mortem: MB=64 single-chunk raised occ 28->37% but busy rose
// +4.2us (U-prologue paid 16x/CU instead of 8x) while idle fell only
// 30->27.4 -- prologue cost and occupancy gain cancelled; test was
// confounded.  R20 separates them:
//  - thin 19.9KB LDS block (8 LDS-able/CU) for occupancy
//  - each block PERSISTENT over NCHUNK=2 consecutive 64-row chunks:
//    U fragments + wds staged ONCE (prologue = champion amortization),
//    grid 2048
//  - launch_bounds(256,5): cap 102 >= ~80 measured need (R19: VGPR 64
//    + acc; zero spill margin ~20) -> 5 waves/SIMD = 5 blocks/CU
// Sentinels: VGPR<=102, FETCH ~2.9MB / WRITE ~1MB (spill=0), LDS 19968.
// Predict: occ 37->45-52%, VALUBusy ~72-75, dur 87.4 -> 78-83.
// Falsify: occ>=45 + dur flat ~86 -> idle is barrier/chain-structural
// -> ~86 is the structure's floor; revert champion or attack the
// exp2->rcp->exp2 serial chain.
// Math (R15, HW-verified): packed-fp32 pairs, fma-folded exp2 algebra,
// cs=CSC*c carried state, 2-wide batched rcp (bound pq<=2^60.2 ->
// products <=2^120.4, hard-safe):
//   p=(1+ei)(1+eg), pq=fma(ef,p,p):  cs' = (cs*p + qw) * rcp(pq)
//   h = om * rcp(dn),  dn=fma(ec,Ao,Ao), ec=exp2(cs')
// 5 exp2 + 1 rcp per cell.  absmax: exactly 1.953125e-3.
// Survey: algebra ladder 133->102->95.8->93.0->91.2->85.9 (R2..R15);
// R16 4-wide rcp flat (latency/throughput cancel); R18 (256,6) spilled
// (1.25GB scratch traffic, 296us); R19 occ 37% / busy +4.2 / flat.

typedef _Float16 f16x8 __attribute__((ext_vector_type(8)));
typedef float f32x4 __attribute__((ext_vector_type(4)));
typedef float f32x2 __attribute__((ext_vector_type(2)));

#define MB 64        // rows per chunk (1 group)
#define NCHUNK 2     // chunks per persistent block
#define NTHREADS 256
#define HSTR 68

__device__ __forceinline__ float ex2(float x) { return __builtin_amdgcn_exp2f(x); }
__device__ __forceinline__ float rcp(float x) { return __builtin_amdgcn_rcpf(x); }
__device__ __forceinline__ f32x2 fma2(f32x2 a, f32x2 b, f32x2 c) {
    return __builtin_elementwise_fma(a, b, c);
}
__device__ __forceinline__ f32x2 ex22(f32x2 a) {
    return (f32x2){ex2(a.x), ex2(a.y)};
}

__global__ __launch_bounds__(NTHREADS, 5) void lstm_fused(
    const float* __restrict__ x,   // [B,5,1]
    const float* __restrict__ W,   // [1,256]  gate order i,f,g,o
    const float* __restrict__ U,   // [64,256]
    const float* __restrict__ b,   // [256]
    const float* __restrict__ Wd,  // [64,1]
    const float* __restrict__ bd,  // [1]
    float* __restrict__ out,       // [B,1]
    int B)
{
    __shared__ _Float16 hbuf[2][64 * HSTR];     // [parity] 17.0 KB
    __shared__ float xs[5][MB];                 // 1.25 KB, [t][row]
    __shared__ float red[4][MB];                // 1 KB
    __shared__ float wds[64];                   // 0.25 KB

    const int tid  = threadIdx.x;
    const int wv   = tid >> 6;
    const int lane = tid & 63;
    const int l15  = lane & 15;
    const int quad = lane >> 4;
    const int base = blockIdx.x * (MB * NCHUNK);

    if (tid < 64) wds[tid] = Wd[tid];

    const float LOG2E = 1.44269504f;
    const float gscale[4] = {-LOG2E, -LOG2E, -2.0f * LOG2E, -LOG2E};
    const float CSC = -2.0f * LOG2E;
    const f32x2 CSC2  = {CSC, CSC};
    const f32x2 NCSC2 = {-CSC, -CSC};

    // U B-fragments loaded ONCE PER BLOCK (amortized over NCHUNK chunks)
    // (n = gate*64 + wv*16 + l15, k = kh*32 + quad*8 + j), scaled,
    // cvt f16, pinned vs remat.
    const int ncol = wv * 16 + l15;
    float Wf[4], bf[4];
    f16x8 Bf[4][2];
#pragma unroll
    for (int g = 0; g < 4; ++g) {
        const int n = g * 64 + ncol;
        const float s = gscale[g];
        Wf[g] = W[n] * s;
        bf[g] = b[n] * s;
#pragma unroll
        for (int kh = 0; kh < 2; ++kh) {
            f16x8 v;
#pragma unroll
            for (int j = 0; j < 8; ++j) {
                const int k = kh * 32 + quad * 8 + j;
                v[j] = (_Float16)(U[k * 256 + n] * s);
            }
            Bf[g][kh] = v;
            asm volatile("" : "+v"(Bf[g][kh]));
        }
    }

    for (int ch = 0; ch < NCHUNK; ++ch) {
        const int row0 = base + ch * MB;

        // stage x transposed to [t][row]
        for (int i = tid; i < MB * 5; i += NTHREADS)
            xs[i % 5][i / 5] = x[row0 * 5 + i];

        // cell state cs = CSC * c: [rt][pair], pair pr covers rows
        // quad*4+2pr+{0,1}
        f32x2 cst[4][2];
#pragma unroll
        for (int a = 0; a < 4; ++a)
#pragma unroll
            for (int pr = 0; pr < 2; ++pr) cst[a][pr] = (f32x2){0.f, 0.f};

        __syncthreads();  // xs visible; also orders hbuf reuse vs prev chunk

        // ---- t = 0 (h=0, c=0): c = i*g, h = o*tanh(c) ----
#pragma unroll
        for (int rt = 0; rt < 4; ++rt) {
            const f32x4 xv = *(const f32x4*)&xs[0][rt * 16 + quad * 4];
            const f32x2 xp0 = {xv[0], xv[1]};
            const f32x2 xp1 = {xv[2], xv[3]};
            const f32x2 wi = {Wf[0], Wf[0]}, bi = {bf[0], bf[0]};
            const f32x2 wg = {Wf[2], Wf[2]}, bg = {bf[2], bf[2]};
            const f32x2 wo = {Wf[3], Wf[3]}, bo = {bf[3], bf[3]};
            const f32x2 ei0 = ex22(fma2(xp0, wi, bi));
            const f32x2 ei1 = ex22(fma2(xp1, wi, bi));
            const f32x2 eg0 = ex22(fma2(xp0, wg, bg));
            const f32x2 eg1 = ex22(fma2(xp1, wg, bg));
            const f32x2 eo0 = ex22(fma2(xp0, wo, bo));
            const f32x2 eo1 = ex22(fma2(xp1, wo, bo));
            // site1 (q=1 at t0): p = (1+ei)(1+eg)
            const f32x2 P0 = ei0 + 1.0f;
            const f32x2 P1 = ei1 + 1.0f;
            const f32x2 p0 = fma2(eg0, P0, P0);
            const f32x2 p1 = fma2(eg1, P1, P1);
            const f32x2 w0 = fma2(eg0, NCSC2, CSC2);   // CSC*(1-eg)
            const f32x2 w1 = fma2(eg1, NCSC2, CSC2);
            const f32x2 m1 = p0 * p1;
            const f32x2 r1 = {rcp(m1.x), rcp(m1.y)};
            const f32x2 cs0 = w0 * (r1 * p1);          // CSC * (i*g)
            const f32x2 cs1 = w1 * (r1 * p0);
            cst[rt][0] = cs0;
            cst[rt][1] = cs1;
            const f32x2 ec0 = ex22(cs0);
            const f32x2 ec1 = ex22(cs1);
            const f32x2 Ao0 = eo0 + 1.0f;
            const f32x2 Ao1 = eo1 + 1.0f;
            const f32x2 dn0 = fma2(ec0, Ao0, Ao0);
            const f32x2 dn1 = fma2(ec1, Ao1, Ao1);
            const f32x2 om0 = 1.0f - ec0;
            const f32x2 om1 = 1.0f - ec1;
            const f32x2 m2 = dn0 * dn1;
            const f32x2 r2 = {rcp(m2.x), rcp(m2.y)};
            const f32x2 h20 = om0 * (r2 * dn1);
            const f32x2 h21 = om1 * (r2 * dn0);
            const int rb = rt * 16 + quad * 4;
            hbuf[0][(rb + 0) * HSTR + ncol] = (_Float16)h20.x;
            hbuf[0][(rb + 1) * HSTR + ncol] = (_Float16)h20.y;
            hbuf[0][(rb + 2) * HSTR + ncol] = (_Float16)h21.x;
            hbuf[0][(rb + 3) * HSTR + ncol] = (_Float16)h21.y;
        }

        // ---- t = 1..4 ----
#pragma unroll
        for (int t = 1; t < 5; ++t) {
            const int src = (t + 1) & 1;
            const int dst = t & 1;
            __syncthreads();
#pragma unroll
            for (int rt = 0; rt < 4; ++rt) {
                const int arow = rt * 16 + l15;   // A layout: m = lane&15
                const f16x8 a0 = *(const f16x8*)&hbuf[src][arow * HSTR + quad * 8];
                const f16x8 a1 = *(const f16x8*)&hbuf[src][arow * HSTR + 32 + quad * 8];
                const f32x4 xv = *(const f32x4*)&xs[t][rt * 16 + quad * 4];
                const f32x2 xlo = {xv[0], xv[1]};
                const f32x2 xhi = {xv[2], xv[3]};
                f32x4 acc[4];
#pragma unroll
                for (int g = 0; g < 4; ++g) {
                    const f32x2 wgv = {Wf[g], Wf[g]};
                    const f32x2 bgv = {bf[g], bf[g]};
                    const f32x2 zlo = fma2(xlo, wgv, bgv);
                    const f32x2 zhi = fma2(xhi, wgv, bgv);
                    f32x4 z = {zlo.x, zlo.y, zhi.x, zhi.y};
                    z = __builtin_amdgcn_mfma_f32_16x16x32_f16(a0, Bf[g][0], z, 0, 0, 0);
                    z = __builtin_amdgcn_mfma_f32_16x16x32_f16(a1, Bf[g][1], z, 0, 0, 0);
                    acc[g] = z;
                }
                // dual-pair cell math, 2-wide batched rcp (R15-verified)
                const f32x2 ei0 = {ex2(acc[0][0]), ex2(acc[0][1])};
                const f32x2 ei1 = {ex2(acc[0][2]), ex2(acc[0][3])};
                const f32x2 ef0 = {ex2(acc[1][0]), ex2(acc[1][1])};
                const f32x2 ef1 = {ex2(acc[1][2]), ex2(acc[1][3])};
                const f32x2 eg0 = {ex2(acc[2][0]), ex2(acc[2][1])};
                const f32x2 eg1 = {ex2(acc[2][2]), ex2(acc[2][3])};
                const f32x2 eo0 = {ex2(acc[3][0]), ex2(acc[3][1])};
                const f32x2 eo1 = {ex2(acc[3][2]), ex2(acc[3][3])};
                const f32x2 P0 = ei0 + 1.0f;
                const f32x2 P1 = ei1 + 1.0f;
                const f32x2 p0 = fma2(eg0, P0, P0);        // (1+ei)(1+eg)
                const f32x2 p1 = fma2(eg1, P1, P1);
                const f32x2 w0 = fma2(eg0, NCSC2, CSC2);   // CSC*(1-eg)
                const f32x2 w1 = fma2(eg1, NCSC2, CSC2);
                const f32x2 qw0 = fma2(ef0, w0, w0);       // q*w
                const f32x2 qw1 = fma2(ef1, w1, w1);
                const f32x2 nums0 = fma2(cst[rt][0], p0, qw0);  // CSC*num
                const f32x2 nums1 = fma2(cst[rt][1], p1, qw1);
                const f32x2 pq0 = fma2(ef0, p0, p0);       // p*q
                const f32x2 pq1 = fma2(ef1, p1, p1);
                const f32x2 m1 = pq0 * pq1;
                const f32x2 r1 = {rcp(m1.x), rcp(m1.y)};
                const f32x2 cs0 = nums0 * (r1 * pq1);      // CSC*c'
                const f32x2 cs1 = nums1 * (r1 * pq0);
                cst[rt][0] = cs0;
                cst[rt][1] = cs1;
                const f32x2 ec0 = ex22(cs0);
                const f32x2 ec1 = ex22(cs1);
                const f32x2 Ao0 = eo0 + 1.0f;
                const f32x2 Ao1 = eo1 + 1.0f;
                const f32x2 dn0 = fma2(ec0, Ao0, Ao0);     // (1+eo)(1+ec)
                const f32x2 dn1 = fma2(ec1, Ao1, Ao1);
                const f32x2 om0 = 1.0f - ec0;
                const f32x2 om1 = 1.0f - ec1;
                const f32x2 m2 = dn0 * dn1;
                const f32x2 r2 = {rcp(m2.x), rcp(m2.y)};
                const f32x2 h20 = om0 * (r2 * dn1);
                const f32x2 h21 = om1 * (r2 * dn0);
                const int rb = rt * 16 + quad * 4;
                hbuf[dst][(rb + 0) * HSTR + ncol] = (_Float16)h20.x;
                hbuf[dst][(rb + 1) * HSTR + ncol] = (_Float16)h20.y;
                hbuf[dst][(rb + 2) * HSTR + ncol] = (_Float16)h21.x;
                hbuf[dst][(rb + 3) * HSTR + ncol] = (_Float16)h21.y;
            }
        }

        __syncthreads();  // h(t=4) complete in hbuf[0]

        // Dense(1, relu): 4 threads per row, each sums 16 of the 64 units.
        {
            const int row = tid & 63;           // 0..63
            const int qh  = tid >> 6;           // 0..3
            float s = 0.0f;
#pragma unroll
            for (int j = 0; j < 16; ++j)
                s += (float)hbuf[0][row * HSTR + qh * 16 + j] * wds[qh * 16 + j];
            red[qh][row] = s;
        }
        __syncthreads();
        if (tid < MB) {
            const float r = red[0][tid] + red[1][tid] + red[2][tid] + red[3][tid] + bd[0];
            out[row0 + tid] = fmaxf(r, 0.0f);
        }
        // next chunk's leading __syncthreads orders hbuf/xs/red reuse
    }
}

extern "C" void kernel_launch(void* const* d_in, const int* in_sizes, int n_in,
                              void* d_out, int out_size, void* d_ws, size_t ws_size,
                              hipStream_t stream) {
    const float* x  = (const float*)d_in[0];
    const float* W  = (const float*)d_in[1];
    const float* U  = (const float*)d_in[2];
    const float* b  = (const float*)d_in[3];
    const float* Wd = (const float*)d_in[4];
    const float* bd = (const float*)d_in[5];
    float* out = (float*)d_out;
    const int B = in_sizes[0] / 5;
    const int grid = B / (MB * NCHUNK);   // 2048 blocks
    lstm_fused<<<grid, NTHREADS, 0, stream>>>(x, W, U, b, Wd, bd, out, B);
}

// Round 8
// 141.331 us; speedup vs baseline: 2.2719x; 2.2719x over previous
//
#include <hip/hip_runtime.h>

// LSTM(units=64) over T=5, D_IN=1, then Dense(1, relu).
// R21 = R20 persistent-chunk structure at the FEASIBLE bound (256,4).
// Register-feasibility map (R18/R19/R20, counters): live set (arch VGPR
// + AGPR, unified file) is in (102,128]:
//   (256,6) cap 85  -> VGPR 40, 1.25GB scratch, 296us   [spill]
//   (256,5) cap 102 -> VGPR 48, 1.09GB scratch, 273us   [spill]
//   (256,4) cap 128 -> VGPR 64, zero scratch            [feasible]
// R20 never tested occupancy -- it re-tested the allocator.  R21 is the
// clean deconfound: persistent NCHUNK=2 blocks (U staged once, grid
// 2048 = champion amortization; R19 paid +4.2us busy staging U 2x),
// thin 19.9KB LDS block, bound (256,4).
// Decision table: busy ~56us expected.
//   occ>=45 + dur 79-84  -> starvation was real, keep going
//   occ>=45 + dur >=86   -> idle is phase-convoy/chain STRUCTURAL ->
//                           ~85-86 is this structure's floor; revert
//                           R15 champion (85.9) and declare/attack sync
//   FETCH >> 3MB         -> spill; revert champion immediately
// Math (R15, HW-verified): packed-fp32 pairs, fma-folded exp2 algebra,
// cs=CSC*c carried state, 2-wide batched rcp (bound pq<=2^60.2 ->
// products <=2^120.4, hard-safe):
//   p=(1+ei)(1+eg), pq=fma(ef,p,p):  cs' = (cs*p + qw) * rcp(pq)
//   h = om * rcp(dn),  dn=fma(ec,Ao,Ao), ec=exp2(cs')
// 5 exp2 + 1 rcp per cell = trans floor (~49us pipe time at 16cyc/
// wave-instr).  absmax: exactly 1.953125e-3.
// Survey: algebra ladder 133->102->95.8->93.0->91.2->85.9 (R2..R15);
// R16 4-wide rcp flat; R19 thin block: occ 28->37% but busy +4.2us
// (prologue 2x) -> net flat 87.4.

typedef _Float16 f16x8 __attribute__((ext_vector_type(8)));
typedef float f32x4 __attribute__((ext_vector_type(4)));
typedef float f32x2 __attribute__((ext_vector_type(2)));

#define MB 64        // rows per chunk (1 group)
#define NCHUNK 2     // chunks per persistent block
#define NTHREADS 256
#define HSTR 68

__device__ __forceinline__ float ex2(float x) { return __builtin_amdgcn_exp2f(x); }
__device__ __forceinline__ float rcp(float x) { return __builtin_amdgcn_rcpf(x); }
__device__ __forceinline__ f32x2 fma2(f32x2 a, f32x2 b, f32x2 c) {
    return __builtin_elementwise_fma(a, b, c);
}
__device__ __forceinline__ f32x2 ex22(f32x2 a) {
    return (f32x2){ex2(a.x), ex2(a.y)};
}

__global__ __launch_bounds__(NTHREADS, 4) void lstm_fused(
    const float* __restrict__ x,   // [B,5,1]
    const float* __restrict__ W,   // [1,256]  gate order i,f,g,o
    const float* __restrict__ U,   // [64,256]
    const float* __restrict__ b,   // [256]
    const float* __restrict__ Wd,  // [64,1]
    const float* __restrict__ bd,  // [1]
    float* __restrict__ out,       // [B,1]
    int B)
{
    __shared__ _Float16 hbuf[2][64 * HSTR];     // [parity] 17.0 KB
    __shared__ float xs[5][MB];                 // 1.25 KB, [t][row]
    __shared__ float red[4][MB];                // 1 KB
    __shared__ float wds[64];                   // 0.25 KB

    const int tid  = threadIdx.x;
    const int wv   = tid >> 6;
    const int lane = tid & 63;
    const int l15  = lane & 15;
    const int quad = lane >> 4;
    const int base = blockIdx.x * (MB * NCHUNK);

    if (tid < 64) wds[tid] = Wd[tid];

    const float LOG2E = 1.44269504f;
    const float gscale[4] = {-LOG2E, -LOG2E, -2.0f * LOG2E, -LOG2E};
    const float CSC = -2.0f * LOG2E;
    const f32x2 CSC2  = {CSC, CSC};
    const f32x2 NCSC2 = {-CSC, -CSC};

    // U B-fragments loaded ONCE PER BLOCK (amortized over NCHUNK chunks)
    // (n = gate*64 + wv*16 + l15, k = kh*32 + quad*8 + j), scaled,
    // cvt f16, pinned vs remat.
    const int ncol = wv * 16 + l15;
    float Wf[4], bf[4];
    f16x8 Bf[4][2];
#pragma unroll
    for (int g = 0; g < 4; ++g) {
        const int n = g * 64 + ncol;
        const float s = gscale[g];
        Wf[g] = W[n] * s;
        bf[g] = b[n] * s;
#pragma unroll
        for (int kh = 0; kh < 2; ++kh) {
            f16x8 v;
#pragma unroll
            for (int j = 0; j < 8; ++j) {
                const int k = kh * 32 + quad * 8 + j;
                v[j] = (_Float16)(U[k * 256 + n] * s);
            }
            Bf[g][kh] = v;
            asm volatile("" : "+v"(Bf[g][kh]));
        }
    }

    for (int ch = 0; ch < NCHUNK; ++ch) {
        const int row0 = base + ch * MB;

        // stage x transposed to [t][row]
        for (int i = tid; i < MB * 5; i += NTHREADS)
            xs[i % 5][i / 5] = x[row0 * 5 + i];

        // cell state cs = CSC * c: [rt][pair], pair pr covers rows
        // quad*4+2pr+{0,1}
        f32x2 cst[4][2];
#pragma unroll
        for (int a = 0; a < 4; ++a)
#pragma unroll
            for (int pr = 0; pr < 2; ++pr) cst[a][pr] = (f32x2){0.f, 0.f};

        __syncthreads();  // xs visible; also orders hbuf reuse vs prev chunk

        // ---- t = 0 (h=0, c=0): c = i*g, h = o*tanh(c) ----
#pragma unroll
        for (int rt = 0; rt < 4; ++rt) {
            const f32x4 xv = *(const f32x4*)&xs[0][rt * 16 + quad * 4];
            const f32x2 xp0 = {xv[0], xv[1]};
            const f32x2 xp1 = {xv[2], xv[3]};
            const f32x2 wi = {Wf[0], Wf[0]}, bi = {bf[0], bf[0]};
            const f32x2 wg = {Wf[2], Wf[2]}, bg = {bf[2], bf[2]};
            const f32x2 wo = {Wf[3], Wf[3]}, bo = {bf[3], bf[3]};
            const f32x2 ei0 = ex22(fma2(xp0, wi, bi));
            const f32x2 ei1 = ex22(fma2(xp1, wi, bi));
            const f32x2 eg0 = ex22(fma2(xp0, wg, bg));
            const f32x2 eg1 = ex22(fma2(xp1, wg, bg));
            const f32x2 eo0 = ex22(fma2(xp0, wo, bo));
            const f32x2 eo1 = ex22(fma2(xp1, wo, bo));
            // site1 (q=1 at t0): p = (1+ei)(1+eg)
            const f32x2 P0 = ei0 + 1.0f;
            const f32x2 P1 = ei1 + 1.0f;
            const f32x2 p0 = fma2(eg0, P0, P0);
            const f32x2 p1 = fma2(eg1, P1, P1);
            const f32x2 w0 = fma2(eg0, NCSC2, CSC2);   // CSC*(1-eg)
            const f32x2 w1 = fma2(eg1, NCSC2, CSC2);
            const f32x2 m1 = p0 * p1;
            const f32x2 r1 = {rcp(m1.x), rcp(m1.y)};
            const f32x2 cs0 = w0 * (r1 * p1);          // CSC * (i*g)
            const f32x2 cs1 = w1 * (r1 * p0);
            cst[rt][0] = cs0;
            cst[rt][1] = cs1;
            const f32x2 ec0 = ex22(cs0);
            const f32x2 ec1 = ex22(cs1);
            const f32x2 Ao0 = eo0 + 1.0f;
            const f32x2 Ao1 = eo1 + 1.0f;
            const f32x2 dn0 = fma2(ec0, Ao0, Ao0);
            const f32x2 dn1 = fma2(ec1, Ao1, Ao1);
            const f32x2 om0 = 1.0f - ec0;
            const f32x2 om1 = 1.0f - ec1;
            const f32x2 m2 = dn0 * dn1;
            const f32x2 r2 = {rcp(m2.x), rcp(m2.y)};
            const f32x2 h20 = om0 * (r2 * dn1);
            const f32x2 h21 = om1 * (r2 * dn0);
            const int rb = rt * 16 + quad * 4;
            hbuf[0][(rb + 0) * HSTR + ncol] = (_Float16)h20.x;
            hbuf[0][(rb + 1) * HSTR + ncol] = (_Float16)h20.y;
            hbuf[0][(rb + 2) * HSTR + ncol] = (_Float16)h21.x;
            hbuf[0][(rb + 3) * HSTR + ncol] = (_Float16)h21.y;
        }

        // ---- t = 1..4 ----
#pragma unroll
        for (int t = 1; t < 5; ++t) {
            const int src = (t + 1) & 1;
            const int dst = t & 1;
            __syncthreads();
#pragma unroll
            for (int rt = 0; rt < 4; ++rt) {
                const int arow = rt * 16 + l15;   // A layout: m = lane&15
                const f16x8 a0 = *(const f16x8*)&hbuf[src][arow * HSTR + quad * 8];
                const f16x8 a1 = *(const f16x8*)&hbuf[src][arow * HSTR + 32 + quad * 8];
                const f32x4 xv = *(const f32x4*)&xs[t][rt * 16 + quad * 4];
                const f32x2 xlo = {xv[0], xv[1]};
                const f32x2 xhi = {xv[2], xv[3]};
                f32x4 acc[4];
#pragma unroll
                for (int g = 0; g < 4; ++g) {
                    const f32x2 wgv = {Wf[g], Wf[g]};
                    const f32x2 bgv = {bf[g], bf[g]};
                    const f32x2 zlo = fma2(xlo, wgv, bgv);
                    const f32x2 zhi = fma2(xhi, wgv, bgv);
                    f32x4 z = {zlo.x, zlo.y, zhi.x, zhi.y};
                    z = __builtin_amdgcn_mfma_f32_16x16x32_f16(a0, Bf[g][0], z, 0, 0, 0);
                    z = __builtin_amdgcn_mfma_f32_16x16x32_f16(a1, Bf[g][1], z, 0, 0, 0);
                    acc[g] = z;
                }
                // dual-pair cell math, 2-wide batched rcp (R15-verified)
                const f32x2 ei0 = {ex2(acc[0][0]), ex2(acc[0][1])};
                const f32x2 ei1 = {ex2(acc[0][2]), ex2(acc[0][3])};
                const f32x2 ef0 = {ex2(acc[1][0]), ex2(acc[1][1])};
                const f32x2 ef1 = {ex2(acc[1][2]), ex2(acc[1][3])};
                const f32x2 eg0 = {ex2(acc[2][0]), ex2(acc[2][1])};
                const f32x2 eg1 = {ex2(acc[2][2]), ex2(acc[2][3])};
                const f32x2 eo0 = {ex2(acc[3][0]), ex2(acc[3][1])};
                const f32x2 eo1 = {ex2(acc[3][2]), ex2(acc[3][3])};
                const f32x2 P0 = ei0 + 1.0f;
                const f32x2 P1 = ei1 + 1.0f;
                const f32x2 p0 = fma2(eg0, P0, P0);        // (1+ei)(1+eg)
                const f32x2 p1 = fma2(eg1, P1, P1);
                const f32x2 w0 = fma2(eg0, NCSC2, CSC2);   // CSC*(1-eg)
                const f32x2 w1 = fma2(eg1, NCSC2, CSC2);
                const f32x2 qw0 = fma2(ef0, w0, w0);       // q*w
                const f32x2 qw1 = fma2(ef1, w1, w1);
                const f32x2 nums0 = fma2(cst[rt][0], p0, qw0);  // CSC*num
                const f32x2 nums1 = fma2(cst[rt][1], p1, qw1);
                const f32x2 pq0 = fma2(ef0, p0, p0);       // p*q
                const f32x2 pq1 = fma2(ef1, p1, p1);
                const f32x2 m1 = pq0 * pq1;
                const f32x2 r1 = {rcp(m1.x), rcp(m1.y)};
                const f32x2 cs0 = nums0 * (r1 * pq1);      // CSC*c'
                const f32x2 cs1 = nums1 * (r1 * pq0);
                cst[rt][0] = cs0;
                cst[rt][1] = cs1;
                const f32x2 ec0 = ex22(cs0);
                const f32x2 ec1 = ex22(cs1);
                const f32x2 Ao0 = eo0 + 1.0f;
                const f32x2 Ao1 = eo1 + 1.0f;
                const f32x2 dn0 = fma2(ec0, Ao0, Ao0);     // (1+eo)(1+ec)
                const f32x2 dn1 = fma2(ec1, Ao1, Ao1);
                const f32x2 om0 = 1.0f - ec0;
                const f32x2 om1 = 1.0f - ec1;
                const f32x2 m2 = dn0 * dn1;
                const f32x2 r2 = {rcp(m2.x), rcp(m2.y)};
                const f32x2 h20 = om0 * (r2 * dn1);
                const f32x2 h21 = om1 * (r2 * dn0);
                const int rb = rt * 16 + quad * 4;
                hbuf[dst][(rb + 0) * HSTR + ncol] = (_Float16)h20.x;
                hbuf[dst][(rb + 1) * HSTR + ncol] = (_Float16)h20.y;
                hbuf[dst][(rb + 2) * HSTR + ncol] = (_Float16)h21.x;
                hbuf[dst][(rb + 3) * HSTR + ncol] = (_Float16)h21.y;
            }
        }

        __syncthreads();  // h(t=4) complete in hbuf[0]

        // Dense(1, relu): 4 threads per row, each sums 16 of the 64 units.
        {
            const int row = tid & 63;           // 0..63
            const int qh  = tid >> 6;           // 0..3
            float s = 0.0f;
#pragma unroll
            for (int j = 0; j < 16; ++j)
                s += (float)hbuf[0][row * HSTR + qh * 16 + j] * wds[qh * 16 + j];
            red[qh][row] = s;
        }
        __syncthreads();
        if (tid < MB) {
            const float r = red[0][tid] + red[1][tid] + red[2][tid] + red[3][tid] + bd[0];
            out[row0 + tid] = fmaxf(r, 0.0f);
        }
        // next chunk's leading __syncthreads orders hbuf/xs/red reuse
    }
}

extern "C" void kernel_launch(void* const* d_in, const int* in_sizes, int n_in,
                              void* d_out, int out_size, void* d_ws, size_t ws_size,
                              hipStream_t stream) {
    const float* x  = (const float*)d_in[0];
    const float* W  = (const float*)d_in[1];
    const float* U  = (const float*)d_in[2];
    const float* b  = (const float*)d_in[3];
    const float* Wd = (const float*)d_in[4];
    const float* bd = (const float*)d_in[5];
    float* out = (float*)d_out;
    const int B = in_sizes[0] / 5;
    const int grid = B / (MB * NCHUNK);   // 2048 blocks
    lstm_fused<<<grid, NTHREADS, 0, stream>>>(x, W, U, b, Wd, bd, out, B);
}

// Round 10
// 133.896 us; speedup vs baseline: 2.3981x; 1.0555x over previous
//
#include <hip/hip_runtime.h>

// LSTM(units=64) over T=5, D_IN=1, then Dense(1, relu).
// R23 = CHAMPION RESUBMIT (R15 verbatim, byte-identical to R22).
// R22 run FAILED only at the post-timing replay check (initial absmax
// passed at 1.953e-3 as always); run telemetry was pathological
// (push_in 185s vs 1e-6 typical, total 472s; session has 2 prior hard
// container failures).  Full race re-audit found no ordering hole:
// every cross-wave read/write pair is barrier-separated in uniform
// control flow, src!=dst parity strictly alternates, and this exact
// binary passed the full harness (incl. the same replay tripwire) >=5
// times (R1/R2/R4 + prior session).  Verdict: presumed infra flake;
// must reproduce before restructuring.
// Pre-registered decision:
//   PASS -> structure confirmed at its chain-structural floor
//     (trans-pipe ~50us of 86us wall = 58% fill; algebra floor 5 exp2
//     + 1 rcp/cell; occupancy FALSIFIED R18-R21: feasible live set
//     (102,128] regs, thin/persistent blocks all flat-or-worse;
//     rt-pair fusion flat R16/17; row partition, software exp2
//     regressed) -> declare roofline.
//   SAME post-timing divergence -> real rare race: next kernel moves
//     to single-buffer hbuf with TWO barriers per timestep (read-phase
//     + write-phase) to remove any src/dst coupling.
// Math (HW-verified R15): packed-fp32 pairs, fma-folded exp2 algebra,
// cs=CSC*c carried state, 2-wide batched rcp (pq<=2^60.2 -> products
// <=2^120.4 hard-safe):
//   p=(1+ei)(1+eg), pq=fma(ef,p,p):  cs' = (cs*p + qw) * rcp(pq)
//   h = om * rcp(dn),  dn=fma(ec,Ao,Ao), ec=exp2(cs')
// Survey ladder (rocprof best): 133 -> 102 -> 95.8 -> 93.0 -> 91.2 ->
// 85.9 (R15) -> R16-R21 all flat/worse.
// absmax: exactly 1.953125e-3 (f16 h round-trip quantization).

typedef _Float16 f16x8 __attribute__((ext_vector_type(8)));
typedef float f32x4 __attribute__((ext_vector_type(4)));
typedef float f32x2 __attribute__((ext_vector_type(2)));

#define MB 128       // rows per block (2 groups of 64)
#define NTHREADS 256
#define HSTR 68

__device__ __forceinline__ float ex2(float x) { return __builtin_amdgcn_exp2f(x); }
__device__ __forceinline__ float rcp(float x) { return __builtin_amdgcn_rcpf(x); }
__device__ __forceinline__ f32x2 fma2(f32x2 a, f32x2 b, f32x2 c) {
    return __builtin_elementwise_fma(a, b, c);
}
__device__ __forceinline__ f32x2 ex22(f32x2 a) {
    return (f32x2){ex2(a.x), ex2(a.y)};
}

__global__ __launch_bounds__(NTHREADS, 3) void lstm_fused(
    const float* __restrict__ x,   // [B,5,1]
    const float* __restrict__ W,   // [1,256]  gate order i,f,g,o
    const float* __restrict__ U,   // [64,256]
    const float* __restrict__ b,   // [256]
    const float* __restrict__ Wd,  // [64,1]
    const float* __restrict__ bd,  // [1]
    float* __restrict__ out,       // [B,1]
    int B)
{
    __shared__ _Float16 hbuf[2][2][64 * HSTR];  // [group][parity] 34.0 KB
    __shared__ float xs[5][MB];                 // 2.5 KB, [t][row]
    __shared__ float red[2][MB];                // 1 KB
    __shared__ float wds[64];                   // 0.25 KB

    const int tid  = threadIdx.x;
    const int wv   = tid >> 6;
    const int lane = tid & 63;
    const int l15  = lane & 15;
    const int quad = lane >> 4;
    const int row0 = blockIdx.x * MB;

    // stage x transposed to [t][row]; stage Wd
    for (int i = tid; i < MB * 5; i += NTHREADS)
        xs[i % 5][i / 5] = x[row0 * 5 + i];
    if (tid < 64) wds[tid] = Wd[tid];

    const float LOG2E = 1.44269504f;
    const float gscale[4] = {-LOG2E, -LOG2E, -2.0f * LOG2E, -LOG2E};
    const float CSC = -2.0f * LOG2E;
    const f32x2 CSC2  = {CSC, CSC};
    const f32x2 NCSC2 = {-CSC, -CSC};

    // U B-fragments loaded ONCE (n = gate*64 + wv*16 + l15,
    // k = kh*32 + quad*8 + j), scaled, cvt f16, pinned vs remat.
    const int ncol = wv * 16 + l15;
    float Wf[4], bf[4];
    f16x8 Bf[4][2];
#pragma unroll
    for (int g = 0; g < 4; ++g) {
        const int n = g * 64 + ncol;
        const float s = gscale[g];
        Wf[g] = W[n] * s;
        bf[g] = b[n] * s;
#pragma unroll
        for (int kh = 0; kh < 2; ++kh) {
            f16x8 v;
#pragma unroll
            for (int j = 0; j < 8; ++j) {
                const int k = kh * 32 + quad * 8 + j;
                v[j] = (_Float16)(U[k * 256 + n] * s);
            }
            Bf[g][kh] = v;
            asm volatile("" : "+v"(Bf[g][kh]));
        }
    }

    // cell state cs = CSC * c: [group][rt][pair], pair pr covers
    // rows quad*4+2pr+{0,1}
    f32x2 cst[2][4][2];
#pragma unroll
    for (int gr = 0; gr < 2; ++gr)
#pragma unroll
        for (int a = 0; a < 4; ++a)
#pragma unroll
            for (int pr = 0; pr < 2; ++pr) cst[gr][a][pr] = (f32x2){0.f, 0.f};

    __syncthreads();  // xs visible

    // ---- t = 0 (h=0, c=0): c = i*g, h = o*tanh(c) ----
#pragma unroll
    for (int gr = 0; gr < 2; ++gr) {
#pragma unroll
        for (int rt = 0; rt < 4; ++rt) {
            const f32x4 xv = *(const f32x4*)&xs[0][gr * 64 + rt * 16 + quad * 4];
            const f32x2 xp0 = {xv[0], xv[1]};
            const f32x2 xp1 = {xv[2], xv[3]};
            const f32x2 wi = {Wf[0], Wf[0]}, bi = {bf[0], bf[0]};
            const f32x2 wg = {Wf[2], Wf[2]}, bg = {bf[2], bf[2]};
            const f32x2 wo = {Wf[3], Wf[3]}, bo = {bf[3], bf[3]};
            const f32x2 zi0 = fma2(xp0, wi, bi), zi1 = fma2(xp1, wi, bi);
            const f32x2 zg0 = fma2(xp0, wg, bg), zg1 = fma2(xp1, wg, bg);
            const f32x2 zo0 = fma2(xp0, wo, bo), zo1 = fma2(xp1, wo, bo);
            const f32x2 ei0 = ex22(zi0);
            const f32x2 ei1 = ex22(zi1);
            const f32x2 eg0 = ex22(zg0);
            const f32x2 eg1 = ex22(zg1);
            const f32x2 eo0 = ex22(zo0);
            const f32x2 eo1 = ex22(zo1);
            // site1 (q=1 at t0): pq = p = (1+ei)(1+eg)
            const f32x2 P0 = ei0 + 1.0f;
            const f32x2 P1 = ei1 + 1.0f;
            const f32x2 p0 = fma2(eg0, P0, P0);
            const f32x2 p1 = fma2(eg1, P1, P1);
            const f32x2 w0 = fma2(eg0, NCSC2, CSC2);   // CSC*(1-eg)
            const f32x2 w1 = fma2(eg1, NCSC2, CSC2);
            const f32x2 m1 = p0 * p1;
            const f32x2 r1 = {rcp(m1.x), rcp(m1.y)};
            const f32x2 cs0 = w0 * (r1 * p1);          // CSC * (i*g)
            const f32x2 cs1 = w1 * (r1 * p0);
            cst[gr][rt][0] = cs0;
            cst[gr][rt][1] = cs1;
            const f32x2 ec0 = ex22(cs0);
            const f32x2 ec1 = ex22(cs1);
            const f32x2 Ao0 = eo0 + 1.0f;
            const f32x2 Ao1 = eo1 + 1.0f;
            const f32x2 dn0 = fma2(ec0, Ao0, Ao0);
            const f32x2 dn1 = fma2(ec1, Ao1, Ao1);
            const f32x2 om0 = 1.0f - ec0;
            const f32x2 om1 = 1.0f - ec1;
            const f32x2 m2 = dn0 * dn1;
            const f32x2 r2 = {rcp(m2.x), rcp(m2.y)};
            const f32x2 h20 = om0 * (r2 * dn1);
            const f32x2 h21 = om1 * (r2 * dn0);
            const int rb = rt * 16 + quad * 4;
            hbuf[gr][0][(rb + 0) * HSTR + ncol] = (_Float16)h20.x;
            hbuf[gr][0][(rb + 1) * HSTR + ncol] = (_Float16)h20.y;
            hbuf[gr][0][(rb + 2) * HSTR + ncol] = (_Float16)h21.x;
            hbuf[gr][0][(rb + 3) * HSTR + ncol] = (_Float16)h21.y;
        }
    }

    // ---- t = 1..4 ----
#pragma unroll
    for (int t = 1; t < 5; ++t) {
        const int src = (t + 1) & 1;
        const int dst = t & 1;
        __syncthreads();
#pragma unroll
        for (int gr = 0; gr < 2; ++gr) {
#pragma unroll
            for (int rt = 0; rt < 4; ++rt) {
                const int arow = rt * 16 + l15;   // A layout: m = lane&15
                const f16x8 a0 = *(const f16x8*)&hbuf[gr][src][arow * HSTR + quad * 8];
                const f16x8 a1 = *(const f16x8*)&hbuf[gr][src][arow * HSTR + 32 + quad * 8];
                const f32x4 xv = *(const f32x4*)&xs[t][gr * 64 + rt * 16 + quad * 4];
                const f32x2 xlo = {xv[0], xv[1]};
                const f32x2 xhi = {xv[2], xv[3]};
                f32x4 acc[4];
#pragma unroll
                for (int g = 0; g < 4; ++g) {
                    const f32x2 wg = {Wf[g], Wf[g]};
                    const f32x2 bg = {bf[g], bf[g]};
                    const f32x2 zlo = fma2(xlo, wg, bg);
                    const f32x2 zhi = fma2(xhi, wg, bg);
                    f32x4 z = {zlo.x, zlo.y, zhi.x, zhi.y};
                    z = __builtin_amdgcn_mfma_f32_16x16x32_f16(a0, Bf[g][0], z, 0, 0, 0);
                    z = __builtin_amdgcn_mfma_f32_16x16x32_f16(a1, Bf[g][1], z, 0, 0, 0);
                    acc[g] = z;
                }
                // dual-pair cell math (pairs pr=0 -> acc[..][0,1],
                // pr=1 -> acc[..][2,3]); 2-wide batched reciprocals.
                const f32x2 ei0 = {ex2(acc[0][0]), ex2(acc[0][1])};
                const f32x2 ei1 = {ex2(acc[0][2]), ex2(acc[0][3])};
                const f32x2 ef0 = {ex2(acc[1][0]), ex2(acc[1][1])};
                const f32x2 ef1 = {ex2(acc[1][2]), ex2(acc[1][3])};
                const f32x2 eg0 = {ex2(acc[2][0]), ex2(acc[2][1])};
                const f32x2 eg1 = {ex2(acc[2][2]), ex2(acc[2][3])};
                const f32x2 eo0 = {ex2(acc[3][0]), ex2(acc[3][1])};
                const f32x2 eo1 = {ex2(acc[3][2]), ex2(acc[3][3])};
                const f32x2 P0 = ei0 + 1.0f;
                const f32x2 P1 = ei1 + 1.0f;
                const f32x2 p0 = fma2(eg0, P0, P0);        // (1+ei)(1+eg)
                const f32x2 p1 = fma2(eg1, P1, P1);
                const f32x2 w0 = fma2(eg0, NCSC2, CSC2);   // CSC*(1-eg)
                const f32x2 w1 = fma2(eg1, NCSC2, CSC2);
                const f32x2 qw0 = fma2(ef0, w0, w0);       // q*w
                const f32x2 qw1 = fma2(ef1, w1, w1);
                const f32x2 nums0 = fma2(cst[gr][rt][0], p0, qw0);  // CSC*num
                const f32x2 nums1 = fma2(cst[gr][rt][1], p1, qw1);
                const f32x2 pq0 = fma2(ef0, p0, p0);       // p*q
                const f32x2 pq1 = fma2(ef1, p1, p1);
                const f32x2 m1 = pq0 * pq1;
                const f32x2 r1 = {rcp(m1.x), rcp(m1.y)};
                const f32x2 cs0 = nums0 * (r1 * pq1);      // CSC*c'
                const f32x2 cs1 = nums1 * (r1 * pq0);
                cst[gr][rt][0] = cs0;
                cst[gr][rt][1] = cs1;
                const f32x2 ec0 = ex22(cs0);
                const f32x2 ec1 = ex22(cs1);
                const f32x2 Ao0 = eo0 + 1.0f;
                const f32x2 Ao1 = eo1 + 1.0f;
                const f32x2 dn0 = fma2(ec0, Ao0, Ao0);     // (1+eo)(1+ec)
                const f32x2 dn1 = fma2(ec1, Ao1, Ao1);
                const f32x2 om0 = 1.0f - ec0;
                const f32x2 om1 = 1.0f - ec1;
                const f32x2 m2 = dn0 * dn1;
                const f32x2 r2 = {rcp(m2.x), rcp(m2.y)};
                const f32x2 h20 = om0 * (r2 * dn1);
                const f32x2 h21 = om1 * (r2 * dn0);
                const int rb = rt * 16 + quad * 4;
                hbuf[gr][dst][(rb + 0) * HSTR + ncol] = (_Float16)h20.x;
                hbuf[gr][dst][(rb + 1) * HSTR + ncol] = (_Float16)h20.y;
                hbuf[gr][dst][(rb + 2) * HSTR + ncol] = (_Float16)h21.x;
                hbuf[gr][dst][(rb + 3) * HSTR + ncol] = (_Float16)h21.y;
            }
        }
    }

    __syncthreads();  // h(t=4) complete in hbuf[*][0]

    // Dense(1, relu): each thread sums 32 of the 64 units for one row.
    {
        const int row = tid & 127;          // 0..127
        const int qh  = tid >> 7;           // 0..1
        const int gr  = row >> 6;
        const int rl  = row & 63;
        float s = 0.0f;
#pragma unroll
        for (int j = 0; j < 32; ++j)
            s += (float)hbuf[gr][0][rl * HSTR + qh * 32 + j] * wds[qh * 32 + j];
        red[qh][row] = s;
    }
    __syncthreads();
    if (tid < MB) {
        const float r = red[0][tid] + red[1][tid] + bd[0];
        out[row0 + tid] = fmaxf(r, 0.0f);
    }
}

extern "C" void kernel_launch(void* const* d_in, const int* in_sizes, int n_in,
                              void* d_out, int out_size, void* d_ws, size_t ws_size,
                              hipStream_t stream) {
    const float* x  = (const float*)d_in[0];
    const float* W  = (const float*)d_in[1];
    const float* U  = (const float*)d_in[2];
    const float* b  = (const float*)d_in[3];
    const float* Wd = (const float*)d_in[4];
    const float* bd = (const float*)d_in[5];
    float* out = (float*)d_out;
    const int B = in_sizes[0] / 5;
    const int grid = B / MB;   // 2048 blocks
    lstm_fused<<<grid, NTHREADS, 0, stream>>>(x, W, U, b, Wd, bd, out, B);
}